// Round 3
// baseline (5825.586 us; speedup 1.0000x reference)
//
#include <hip/hip_runtime.h>
#include <math.h>

#define BS 8192
#define SL 49
#define FDIM 11
#define ROWS (BS*SL)

// ---------------- BN stats: sum / sumsq over (BS,SL) for features {0..7,10} ----
__global__ __launch_bounds__(256) void k_stats(const float* __restrict__ inp,
                                               double* __restrict__ gsum) {
  const int nblk = gridDim.x;
  const int per = (ROWS + nblk - 1) / nblk;
  const int r0 = blockIdx.x * per;
  int r1 = r0 + per; if (r1 > ROWS) r1 = ROWS;
  float s[9], q[9];
#pragma unroll
  for (int j = 0; j < 9; ++j) { s[j] = 0.f; q[j] = 0.f; }
  for (int r = r0 + threadIdx.x; r < r1; r += 256) {
    const float* row = inp + r * FDIM;
#pragma unroll
    for (int j = 0; j < 9; ++j) {
      float v = row[j < 8 ? j : 10];
      s[j] += v; q[j] += v * v;
    }
  }
#pragma unroll
  for (int j = 0; j < 9; ++j) {
    for (int off = 32; off; off >>= 1) {
      s[j] += __shfl_down(s[j], off);
      q[j] += __shfl_down(q[j], off);
    }
  }
  __shared__ float red[4][18];
  const int wid = threadIdx.x >> 6;
  const int lane = threadIdx.x & 63;
  if (lane == 0) {
#pragma unroll
    for (int j = 0; j < 9; ++j) { red[wid][j] = s[j]; red[wid][9 + j] = q[j]; }
  }
  __syncthreads();
  if (threadIdx.x < 18) {
    float t = red[0][threadIdx.x] + red[1][threadIdx.x] +
              red[2][threadIdx.x] + red[3][threadIdx.x];
    atomicAdd(&gsum[threadIdx.x], (double)t);
  }
}

// ---------------- finalize BN params + precompute layer-0 q (batch-independent) ----
__global__ __launch_bounds__(256) void k_finalize(const double* __restrict__ gsum,
                           const float* __restrict__ gamma,
                           const float* __restrict__ beta,
                           const float* __restrict__ hidden,
                           const float* __restrict__ Wq,
                           float* __restrict__ bnp,
                           float* __restrict__ q0g) {
  int tid = threadIdx.x;
  if (tid < 9) {
    const double N = (double)ROWS;
    double mean = gsum[tid] / N;
    double msq  = gsum[9 + tid] / N;
    float var = (float)(msq - mean * mean);
    float sc = gamma[tid] / sqrtf(var + 1e-5f);
    bnp[tid] = sc;
    bnp[9 + tid] = beta[tid] - (float)mean * sc;
  }
  // q0[s][i][c] = sum_k hidden[i][k] * Wq[l=0,s][k][c]
  int s = tid >> 7, i2 = (tid >> 6) & 1, c = tid & 63;
  const float* W = Wq + (s << 12);
#pragma unroll
  for (int ii = 0; ii < 2; ++ii) {
    int i = i2 + 2 * ii;
    float a = 0.f;
    for (int k = 0; k < 64; ++k) a += hidden[i * 64 + k] * W[k * 64 + c];
    q0g[s * 256 + i * 64 + c] = a;
  }
}

// ---------------- mega kernel: one block per (batch, stream) ----------------
__global__ __launch_bounds__(256, 4) void k_mega(
    const float* __restrict__ inp, const float* __restrict__ dists,
    const float* __restrict__ bnp, const float* __restrict__ q0g,
    const float* __restrict__ xe_w1, const float* __restrict__ xe_b1,
    const float* __restrict__ xe_w2, const float* __restrict__ xe_b2,
    const float* __restrict__ ye_w1, const float* __restrict__ ye_b1,
    const float* __restrict__ ye_w2, const float* __restrict__ ye_b2,
    const float* __restrict__ learnable_y, const float* __restrict__ hidden_tokens,
    const float* __restrict__ Wq, const float* __restrict__ Wk,
    const float* __restrict__ Wv, const float* __restrict__ Wo,
    const float* __restrict__ Wq2, const float* __restrict__ Wk2,
    const float* __restrict__ Wv2, const float* __restrict__ Wo2,
    float* __restrict__ enc)
{
  __shared__ float raw[49][12];
  __shared__ float cs8[49][8];
  __shared__ float emb[49][64];   // this stream's embedding
  __shared__ float KB[49][68];    // h1, then K (rope'd), then T = a@ctx, then k2/v2
  __shared__ float scb[32][52];   // scores / probs (stride 52 -> 16B aligned)
  __shared__ float Hs[4][64];
  __shared__ float qb[4][64];     // q, then attn-out
  __shared__ float db[48];
  __shared__ float bnl[18];
  __shared__ float q2[64];
  __shared__ float o1[64];
  __shared__ float a2[32];

  const int tid  = threadIdx.x;
  const int lane = tid & 63;
  const int grp  = tid >> 6;
  const int b    = blockIdx.x >> 1;
  const int s    = blockIdx.x & 1;
  const float scale = 0.35355339059327373f;  // 1/sqrt(8)

  for (int i = tid; i < 49 * FDIM; i += 256) raw[i / FDIM][i % FDIM] = inp[b * (49*FDIM) + i];
  if (tid < 18) bnl[tid] = bnp[tid];
  if (tid >= 64 && tid < 112) db[tid - 64] = dists[b * 49 + (tid - 64)];
  __syncthreads();

  if (tid < 49) {
    float x = raw[tid][8], y = raw[tid][9];
    cs8[tid][0] = cosf(10.f * x); cs8[tid][1] = cosf(10.f * y);
    cs8[tid][2] = cosf(x);        cs8[tid][3] = cosf(y);
    cs8[tid][4] = sinf(10.f * x); cs8[tid][5] = sinf(10.f * y);
    cs8[tid][6] = sinf(x);        cs8[tid][7] = sinf(y);
  }
  for (int i = tid; i < 441; i += 256) {   // 49*9
    int t = i / 9, j = i - t * 9;
    int f = (j < 8) ? j : 10;
    raw[t][f] = raw[t][f] * bnl[j] + bnl[9 + j];
  }
  __syncthreads();

  if (s == 0 && tid < 10) enc[b * 138 + 128 + tid] = raw[48][tid];

  // ---- embed layer 1 -> KB
  if (s == 0) {
    const float bias1 = xe_b1[lane];
    float acc[13];
#pragma unroll
    for (int j = 0; j < 13; ++j) acc[j] = bias1;
#pragma unroll
    for (int k = 0; k < 8; ++k) {
      float w = xe_w1[k * 64 + lane];
#pragma unroll
      for (int j = 0; j < 12; ++j) acc[j] += raw[grp + 4 * j][k] * w;
      if (grp == 0) acc[12] += raw[48][k] * w;
    }
#pragma unroll
    for (int j = 0; j < 12; ++j) { float a = acc[j]; KB[grp + 4 * j][lane] = a - tanhf(a); }
    if (grp == 0) { float a = acc[12]; KB[48][lane] = a - tanhf(a); }
  } else {
    const float w1y = ye_w1[lane];
    const float b1y = ye_b1[lane];
#pragma unroll
    for (int j = 0; j < 12; ++j) {
      int t = grp + 4 * j;
      float a = raw[t][10] * w1y + b1y;
      KB[t][lane] = a - tanhf(a);
    }
  }
  __syncthreads();

  // ---- embed layer 2 -> emb ; init Hs
  if (s == 0) {
    const float b2 = xe_b2[lane];
    float acc[13];
#pragma unroll
    for (int j = 0; j < 13; ++j) acc[j] = b2;
    for (int k = 0; k < 64; k += 4) {
      float w0 = xe_w2[(k + 0) * 64 + lane];
      float w1_ = xe_w2[(k + 1) * 64 + lane];
      float w2_ = xe_w2[(k + 2) * 64 + lane];
      float w3_ = xe_w2[(k + 3) * 64 + lane];
#pragma unroll
      for (int j = 0; j < 12; ++j) {
        float4 cv = *(const float4*)&KB[grp + 4 * j][k];
        acc[j] += cv.x * w0 + cv.y * w1_ + cv.z * w2_ + cv.w * w3_;
      }
      if (grp == 0) {
        float4 cv = *(const float4*)&KB[48][k];
        acc[12] += cv.x * w0 + cv.y * w1_ + cv.z * w2_ + cv.w * w3_;
      }
    }
#pragma unroll
    for (int j = 0; j < 12; ++j) emb[grp + 4 * j][lane] = acc[j];
    if (grp == 0) emb[48][lane] = acc[12];
  } else {
    const float b2 = ye_b2[lane];
    float acc[12];
#pragma unroll
    for (int j = 0; j < 12; ++j) acc[j] = b2;
    for (int k = 0; k < 64; k += 4) {
      float w0 = ye_w2[(k + 0) * 64 + lane];
      float w1_ = ye_w2[(k + 1) * 64 + lane];
      float w2_ = ye_w2[(k + 2) * 64 + lane];
      float w3_ = ye_w2[(k + 3) * 64 + lane];
#pragma unroll
      for (int j = 0; j < 12; ++j) {
        float4 cv = *(const float4*)&KB[grp + 4 * j][k];
        acc[j] += cv.x * w0 + cv.y * w1_ + cv.z * w2_ + cv.w * w3_;
      }
    }
#pragma unroll
    for (int j = 0; j < 12; ++j) emb[grp + 4 * j][lane] = acc[j];
    if (tid < 64) emb[48][lane] = learnable_y[lane];
  }
  Hs[grp][lane] = hidden_tokens[grp * 64 + lane];
  __syncthreads();

  // ---- 2 self-attention layers
#pragma unroll 1
  for (int l = 0; l < 2; ++l) {
    const float* Wk_p = Wk + ((l * 2 + s) << 12);
    const float* Wv_p = Wv + ((l * 2 + s) << 12);
    const float* Wo_p = Wo + ((l * 2 + s) << 12);
    // q: layer 0 is batch-independent (precomputed); layer 1 = H @ Wq
    if (l == 0) {
      qb[grp][lane] = q0g[s * 256 + tid];
    } else {
      const float* Wq_p = Wq + ((l * 2 + s) << 12);
      float a = 0.f;
      for (int k = 0; k < 64; k += 4) {
        float4 hv = *(const float4*)&Hs[grp][k];
        a += hv.x * Wq_p[(k + 0) * 64 + lane] + hv.y * Wq_p[(k + 1) * 64 + lane]
           + hv.z * Wq_p[(k + 2) * 64 + lane] + hv.w * Wq_p[(k + 3) * 64 + lane];
      }
      qb[grp][lane] = a;
    }
    // K = rope(ctx @ Wk)  (12 rows per thread)
    {
      float aK[12];
#pragma unroll
      for (int j = 0; j < 12; ++j) aK[j] = 0.f;
      for (int k = 0; k < 64; k += 4) {
        float wk0 = Wk_p[(k + 0) * 64 + lane], wk1 = Wk_p[(k + 1) * 64 + lane];
        float wk2 = Wk_p[(k + 2) * 64 + lane], wk3 = Wk_p[(k + 3) * 64 + lane];
#pragma unroll
        for (int j = 0; j < 12; ++j) {
          float4 cv = *(const float4*)&emb[grp + 4 * j][k];
          aK[j] += cv.x * wk0 + cv.y * wk1 + cv.z * wk2 + cv.w * wk3;
        }
      }
      const int p = (lane >> 1) & 3;
      const int odd = lane & 1;
#pragma unroll
      for (int j = 0; j < 12; ++j) {
        int t = grp + 4 * j;
        float other = __shfl_xor(aK[j], 1);
        float co = cs8[t][p], si = cs8[t][4 + p];
        KB[t][lane] = odd ? (si * other + co * aK[j]) : (co * aK[j] - si * other);
      }
    }
    __syncthreads();
    // scores + bias  (vectorized: q in regs, K rows via b128)
    {
      int r = tid >> 3;
      int h = r >> 2, i = r & 3;
      int t0 = tid & 7;
      float4 qa = *(const float4*)&qb[i][h * 8];
      float4 qc = *(const float4*)&qb[i][h * 8 + 4];
      for (int t = t0; t < 48; t += 8) {
        float4 ka = *(const float4*)&KB[t][h * 8];
        float4 kc = *(const float4*)&KB[t][h * 8 + 4];
        float a = qa.x * ka.x + qa.y * ka.y + qa.z * ka.z + qa.w * ka.w
                + qc.x * kc.x + qc.y * kc.y + qc.z * kc.z + qc.w * kc.w;
        scb[r][t] = a * scale - db[t];
      }
    }
    __syncthreads();
    // softmax: 8 lanes per row
    {
      int r = tid >> 3, l8 = tid & 7;
      float v[6];
      float m = -1e30f;
#pragma unroll
      for (int j = 0; j < 6; ++j) { v[j] = scb[r][l8 + 8 * j]; m = fmaxf(m, v[j]); }
      m = fmaxf(m, __shfl_xor(m, 1));
      m = fmaxf(m, __shfl_xor(m, 2));
      m = fmaxf(m, __shfl_xor(m, 4));
      float sum = 0.f;
#pragma unroll
      for (int j = 0; j < 6; ++j) { v[j] = __expf(v[j] - m); sum += v[j]; }
      sum += __shfl_xor(sum, 1);
      sum += __shfl_xor(sum, 2);
      sum += __shfl_xor(sum, 4);
      float inv = 1.f / sum;
#pragma unroll
      for (int j = 0; j < 6; ++j) scb[r][l8 + 8 * j] = v[j] * inv;
    }
    __syncthreads();
    // T = a @ ctx  (32 x 64) -> KB rows 0..31 ; 2 rows x 4 cols per thread
    {
      const int cq = (tid & 15) << 2;
      const int m0 = (tid >> 4) << 1, m1 = m0 + 1;
      float4 acc0 = {0.f, 0.f, 0.f, 0.f}, acc1 = {0.f, 0.f, 0.f, 0.f};
      for (int tt = 0; tt < 48; tt += 4) {
        float4 a0 = *(const float4*)&scb[m0][tt];
        float4 a1 = *(const float4*)&scb[m1][tt];
        float4 e0 = *(const float4*)&emb[tt + 0][cq];
        float4 e1 = *(const float4*)&emb[tt + 1][cq];
        float4 e2 = *(const float4*)&emb[tt + 2][cq];
        float4 e3 = *(const float4*)&emb[tt + 3][cq];
        acc0.x += a0.x * e0.x + a0.y * e1.x + a0.z * e2.x + a0.w * e3.x;
        acc0.y += a0.x * e0.y + a0.y * e1.y + a0.z * e2.y + a0.w * e3.y;
        acc0.z += a0.x * e0.z + a0.y * e1.z + a0.z * e2.z + a0.w * e3.z;
        acc0.w += a0.x * e0.w + a0.y * e1.w + a0.z * e2.w + a0.w * e3.w;
        acc1.x += a1.x * e0.x + a1.y * e1.x + a1.z * e2.x + a1.w * e3.x;
        acc1.y += a1.x * e0.y + a1.y * e1.y + a1.z * e2.y + a1.w * e3.y;
        acc1.z += a1.x * e0.z + a1.y * e1.z + a1.z * e2.z + a1.w * e3.z;
        acc1.w += a1.x * e0.w + a1.y * e1.w + a1.z * e2.w + a1.w * e3.w;
      }
      *(float4*)&KB[m0][cq] = acc0;
      *(float4*)&KB[m1][cq] = acc1;
    }
    __syncthreads();
    // out[i][lane] = sum_c T[h*4+i][c] * Wv[c][lane]   (h = lane>>3) -> qb
    {
      const int r = ((lane >> 3) << 2) + grp;
      float a = 0.f;
      for (int c = 0; c < 64; c += 4) {
        float4 tv = *(const float4*)&KB[r][c];
        a += tv.x * Wv_p[(c + 0) * 64 + lane] + tv.y * Wv_p[(c + 1) * 64 + lane]
           + tv.z * Wv_p[(c + 2) * 64 + lane] + tv.w * Wv_p[(c + 3) * 64 + lane];
      }
      qb[grp][lane] = a;
    }
    __syncthreads();
    // H += out @ Wo
    {
      float a = Hs[grp][lane];
      for (int k = 0; k < 64; k += 4) {
        float4 av = *(const float4*)&qb[grp][k];
        a += av.x * Wo_p[(k + 0) * 64 + lane] + av.y * Wo_p[(k + 1) * 64 + lane]
           + av.z * Wo_p[(k + 2) * 64 + lane] + av.w * Wo_p[(k + 3) * 64 + lane];
      }
      Hs[grp][lane] = a;
    }
    __syncthreads();
  }

  // ---- final cross attention
  const float* Wq2_p = Wq2 + (s << 12);
  const float* Wk2_p = Wk2 + (s << 12);
  const float* Wv2_p = Wv2 + (s << 12);
  const float* Wo2_p = Wo2 + (s << 12);
  if (tid < 64) {
    float a = 0.f;
    for (int k = 0; k < 64; k += 4) {
      float4 cv = *(const float4*)&emb[48][k];
      a += cv.x * Wq2_p[(k + 0) * 64 + lane] + cv.y * Wq2_p[(k + 1) * 64 + lane]
         + cv.z * Wq2_p[(k + 2) * 64 + lane] + cv.w * Wq2_p[(k + 3) * 64 + lane];
    }
    float other = __shfl_xor(a, 1);
    int p = (lane >> 1) & 3;
    float co = cs8[48][p], si = cs8[48][4 + p];
    q2[lane] = (lane & 1) ? (si * other + co * a) : (co * a - si * other);
  }
  {
    float aK = 0.f, aV = 0.f;
    for (int k = 0; k < 64; k += 4) {
      float4 hv = *(const float4*)&Hs[grp][k];
      aK += hv.x * Wk2_p[(k + 0) * 64 + lane] + hv.y * Wk2_p[(k + 1) * 64 + lane]
          + hv.z * Wk2_p[(k + 2) * 64 + lane] + hv.w * Wk2_p[(k + 3) * 64 + lane];
      aV += hv.x * Wv2_p[(k + 0) * 64 + lane] + hv.y * Wv2_p[(k + 1) * 64 + lane]
          + hv.z * Wv2_p[(k + 2) * 64 + lane] + hv.w * Wv2_p[(k + 3) * 64 + lane];
    }
    KB[grp][lane] = aK;      // k2 rows 0..3
    KB[8 + grp][lane] = aV;  // v2 rows 8..11
  }
  __syncthreads();
  if (tid < 32) {
    int h = tid >> 2, i = tid & 3;
    float4 qa = *(const float4*)&q2[h * 8];
    float4 qc = *(const float4*)&q2[h * 8 + 4];
    float4 ka = *(const float4*)&KB[i][h * 8];
    float4 kc = *(const float4*)&KB[i][h * 8 + 4];
    float a = qa.x * ka.x + qa.y * ka.y + qa.z * ka.z + qa.w * ka.w
            + qc.x * kc.x + qc.y * kc.y + qc.z * kc.z + qc.w * kc.w;
    a *= scale;
    float m = fmaxf(a, __shfl_xor(a, 1));
    m = fmaxf(m, __shfl_xor(m, 2));
    float e = __expf(a - m);
    float sum = e + __shfl_xor(e, 1);
    sum += __shfl_xor(sum, 2);
    a2[tid] = e / sum;
  }
  __syncthreads();
  if (tid < 64) {
    int h = lane >> 3;
    float a = 0.f;
#pragma unroll
    for (int i = 0; i < 4; ++i) a += a2[h * 4 + i] * KB[8 + i][lane];
    o1[lane] = a;
  }
  __syncthreads();
  if (tid < 64) {
    float a = 0.f;
    for (int k = 0; k < 64; k += 4) {
      float4 ov = *(const float4*)&o1[k];
      a += ov.x * Wo2_p[(k + 0) * 64 + lane] + ov.y * Wo2_p[(k + 1) * 64 + lane]
         + ov.z * Wo2_p[(k + 2) * 64 + lane] + ov.w * Wo2_p[(k + 3) * 64 + lane];
    }
    enc[b * 138 + s * 64 + lane] = a;
  }
}

// ---------------- decoder: enc(138) -> 512 -> 256 -> 1, 16 batches/block ----
__global__ __launch_bounds__(256) void k_dec(
    const float* __restrict__ enc,
    const float* __restrict__ w0, const float* __restrict__ b0,
    const float* __restrict__ w1, const float* __restrict__ b1,
    const float* __restrict__ w2, const float* __restrict__ b2,
    float* __restrict__ out)
{
  __shared__ float encs[16][140];
  __shared__ float h0s[16][512];
  __shared__ float h1s[16][256];
  const int tid = threadIdx.x;
  const int rb = blockIdx.x * 16;

  for (int i = tid; i < 16 * 138; i += 256) {
    int r = i / 138, k = i - r * 138;
    encs[r][k] = enc[(rb + r) * 138 + k];
  }
  __syncthreads();
  {
    float acc0[16], acc1[16];
    const float bb0 = b0[tid], bb1 = b0[tid + 256];
#pragma unroll
    for (int r = 0; r < 16; ++r) { acc0[r] = bb0; acc1[r] = bb1; }
    for (int k = 0; k < 136; k += 4) {
      float wa0 = w0[(k + 0) * 512 + tid], wa1 = w0[(k + 1) * 512 + tid];
      float wa2 = w0[(k + 2) * 512 + tid], wa3 = w0[(k + 3) * 512 + tid];
      float wb0 = w0[(k + 0) * 512 + tid + 256], wb1 = w0[(k + 1) * 512 + tid + 256];
      float wb2 = w0[(k + 2) * 512 + tid + 256], wb3 = w0[(k + 3) * 512 + tid + 256];
#pragma unroll
      for (int r = 0; r < 16; ++r) {
        float4 ev = *(const float4*)&encs[r][k];
        acc0[r] += ev.x * wa0 + ev.y * wa1 + ev.z * wa2 + ev.w * wa3;
        acc1[r] += ev.x * wb0 + ev.y * wb1 + ev.z * wb2 + ev.w * wb3;
      }
    }
    for (int k = 136; k < 138; ++k) {
      float wa = w0[k * 512 + tid], wb = w0[k * 512 + tid + 256];
#pragma unroll
      for (int r = 0; r < 16; ++r) {
        float e = encs[r][k];
        acc0[r] += e * wa; acc1[r] += e * wb;
      }
    }
#pragma unroll
    for (int r = 0; r < 16; ++r) {
      float a = acc0[r]; h0s[r][tid] = a - tanhf(a);
      a = acc1[r];       h0s[r][tid + 256] = a - tanhf(a);
    }
  }
  __syncthreads();
  {
    float acc[16];
    const float bb = b1[tid];
#pragma unroll
    for (int r = 0; r < 16; ++r) acc[r] = bb;
    for (int k = 0; k < 512; k += 4) {
      float ww0 = w1[(k + 0) * 256 + tid], ww1 = w1[(k + 1) * 256 + tid];
      float ww2 = w1[(k + 2) * 256 + tid], ww3 = w1[(k + 3) * 256 + tid];
#pragma unroll
      for (int r = 0; r < 16; ++r) {
        float4 hv = *(const float4*)&h0s[r][k];
        acc[r] += hv.x * ww0 + hv.y * ww1 + hv.z * ww2 + hv.w * ww3;
      }
    }
#pragma unroll
    for (int r = 0; r < 16; ++r) { float a = acc[r]; h1s[r][tid] = a - tanhf(a); }
  }
  __syncthreads();
  {
    int r = tid >> 4, l16 = tid & 15;
    float a = 0.f;
    for (int kk = 0; kk < 16; ++kk) {
      int k = l16 + 16 * kk;
      a += h1s[r][k] * w2[k];
    }
    for (int off = 8; off; off >>= 1) a += __shfl_down(a, off, 16);
    if (l16 == 0) out[rb + r] = a + b2[0];
  }
}

extern "C" void kernel_launch(void* const* d_in, const int* in_sizes, int n_in,
                              void* d_out, int out_size, void* d_ws, size_t ws_size,
                              hipStream_t stream) {
  const float* inp        = (const float*)d_in[0];
  const float* dists      = (const float*)d_in[1];
  const float* bn_gamma   = (const float*)d_in[3];
  const float* bn_beta    = (const float*)d_in[4];
  const float* xe_w1      = (const float*)d_in[5];
  const float* xe_b1      = (const float*)d_in[6];
  const float* xe_w2      = (const float*)d_in[7];
  const float* xe_b2      = (const float*)d_in[8];
  const float* ye_w1      = (const float*)d_in[9];
  const float* ye_b1      = (const float*)d_in[10];
  const float* ye_w2      = (const float*)d_in[11];
  const float* ye_b2      = (const float*)d_in[12];
  const float* learnable  = (const float*)d_in[13];
  const float* hidden     = (const float*)d_in[14];
  const float* Wq         = (const float*)d_in[15];
  const float* Wk         = (const float*)d_in[16];
  const float* Wv         = (const float*)d_in[17];
  const float* Wo         = (const float*)d_in[18];
  const float* Wq2        = (const float*)d_in[19];
  const float* Wk2        = (const float*)d_in[20];
  const float* Wv2        = (const float*)d_in[21];
  const float* Wo2        = (const float*)d_in[22];
  const float* dec_w0     = (const float*)d_in[23];
  const float* dec_b0     = (const float*)d_in[24];
  const float* dec_w1     = (const float*)d_in[25];
  const float* dec_b1     = (const float*)d_in[26];
  const float* dec_w2     = (const float*)d_in[27];
  const float* dec_b2     = (const float*)d_in[28];

  double* gsum = (double*)d_ws;                       // 18 doubles @ 0
  float*  bnp  = (float*)((char*)d_ws + 256);         // 18 floats
  float*  q0g  = (float*)((char*)d_ws + 512);         // 2*4*64 floats
  float*  enc  = (float*)((char*)d_ws + 2560);        // 8192*138 floats

  hipMemsetAsync(d_ws, 0, 256, stream);
  k_stats   <<<512, 256, 0, stream>>>(inp, gsum);
  k_finalize<<<1, 256, 0, stream>>>(gsum, bn_gamma, bn_beta, hidden, Wq, bnp, q0g);
  k_mega    <<<BS * 2, 256, 0, stream>>>(inp, dists, bnp, q0g,
                                         xe_w1, xe_b1, xe_w2, xe_b2,
                                         ye_w1, ye_b1, ye_w2, ye_b2,
                                         learnable, hidden,
                                         Wq, Wk, Wv, Wo, Wq2, Wk2, Wv2, Wo2, enc);
  k_dec     <<<BS / 16, 256, 0, stream>>>(enc, dec_w0, dec_b0, dec_w1, dec_b1,
                                          dec_w2, dec_b2, (float*)d_out);
}

// Round 4
// 1026.988 us; speedup vs baseline: 5.6725x; 5.6725x over previous
//
#include <hip/hip_runtime.h>
#include <math.h>

#define BS 8192
#define SL 49
#define FDIM 11
#define ROWS (BS*SL)

// ---------------- BN stats: sum / sumsq over (BS,SL) for features {0..7,10} ----
__global__ __launch_bounds__(256) void k_stats(const float* __restrict__ inp,
                                               double* __restrict__ gsum) {
  const int nblk = gridDim.x;
  const int per = (ROWS + nblk - 1) / nblk;
  const int r0 = blockIdx.x * per;
  int r1 = r0 + per; if (r1 > ROWS) r1 = ROWS;
  float s[9], q[9];
#pragma unroll
  for (int j = 0; j < 9; ++j) { s[j] = 0.f; q[j] = 0.f; }
  for (int r = r0 + threadIdx.x; r < r1; r += 256) {
    const float* row = inp + r * FDIM;
#pragma unroll
    for (int j = 0; j < 9; ++j) {
      float v = row[j < 8 ? j : 10];
      s[j] += v; q[j] += v * v;
    }
  }
#pragma unroll
  for (int j = 0; j < 9; ++j) {
    for (int off = 32; off; off >>= 1) {
      s[j] += __shfl_down(s[j], off);
      q[j] += __shfl_down(q[j], off);
    }
  }
  __shared__ float red[4][18];
  const int wid = threadIdx.x >> 6;
  const int lane = threadIdx.x & 63;
  if (lane == 0) {
#pragma unroll
    for (int j = 0; j < 9; ++j) { red[wid][j] = s[j]; red[wid][9 + j] = q[j]; }
  }
  __syncthreads();
  if (threadIdx.x < 18) {
    float t = red[0][threadIdx.x] + red[1][threadIdx.x] +
              red[2][threadIdx.x] + red[3][threadIdx.x];
    atomicAdd(&gsum[threadIdx.x], (double)t);
  }
}

// ---------------- finalize BN params + precompute layer-0 q (batch-independent) ----
__global__ __launch_bounds__(256) void k_finalize(const double* __restrict__ gsum,
                           const float* __restrict__ gamma,
                           const float* __restrict__ beta,
                           const float* __restrict__ hidden,
                           const float* __restrict__ Wq,
                           float* __restrict__ bnp,
                           float* __restrict__ q0g) {
  int tid = threadIdx.x;
  if (tid < 9) {
    const double N = (double)ROWS;
    double mean = gsum[tid] / N;
    double msq  = gsum[9 + tid] / N;
    float var = (float)(msq - mean * mean);
    float sc = gamma[tid] / sqrtf(var + 1e-5f);
    bnp[tid] = sc;
    bnp[9 + tid] = beta[tid] - (float)mean * sc;
  }
  // q0[s][i][c] = sum_k hidden[i][k] * Wq[l=0,s][k][c]
  int s = tid >> 7, i2 = (tid >> 6) & 1, c = tid & 63;
  const float* W = Wq + (s << 12);
#pragma unroll
  for (int ii = 0; ii < 2; ++ii) {
    int i = i2 + 2 * ii;
    float a = 0.f;
    for (int k = 0; k < 64; ++k) a += hidden[i * 64 + k] * W[k * 64 + c];
    q0g[s * 256 + i * 64 + c] = a;
  }
}

// ---------------- mega kernel: one block per (batch, stream) ----------------
// LDS budget ~39.5 KB -> 4 blocks/CU.
__global__ __launch_bounds__(256, 4) void k_mega(
    const float* __restrict__ inp, const float* __restrict__ dists,
    const float* __restrict__ bnp, const float* __restrict__ q0g,
    const float* __restrict__ xe_w1, const float* __restrict__ xe_b1,
    const float* __restrict__ xe_w2, const float* __restrict__ xe_b2,
    const float* __restrict__ ye_w1, const float* __restrict__ ye_b1,
    const float* __restrict__ ye_w2, const float* __restrict__ ye_b2,
    const float* __restrict__ learnable_y, const float* __restrict__ hidden_tokens,
    const float* __restrict__ Wq, const float* __restrict__ Wk,
    const float* __restrict__ Wv, const float* __restrict__ Wo,
    const float* __restrict__ Wq2, const float* __restrict__ Wk2,
    const float* __restrict__ Wv2, const float* __restrict__ Wo2,
    float* __restrict__ enc)
{
  __shared__ float raw[49][12];
  __shared__ float cs8[49][8];
  __shared__ float emb[49][64];   // this stream's embedding (ctx rows 0..47, qry row 48)
  __shared__ float KB[49][68];    // staged h1, then K (rope'd), then T = a@ctx, then k2/v2
  __shared__ float scb[32][52];   // scores / softmax probs (row stride 52 -> 16B aligned)
  __shared__ float Hs[4][64];
  __shared__ float qb[4][64];     // q, then attn-out
  __shared__ float db[48];
  __shared__ float bnl[18];
  __shared__ float q2[64];
  __shared__ float o1[64];
  __shared__ float a2[32];

  const int tid  = threadIdx.x;
  const int lane = tid & 63;
  const int grp  = tid >> 6;
  const int b    = blockIdx.x >> 1;
  const int s    = blockIdx.x & 1;
  const float scale = 0.35355339059327373f;  // 1/sqrt(8)

  // ---- load input rows, bn params, dists
  for (int i = tid; i < 49 * FDIM; i += 256) raw[i / FDIM][i % FDIM] = inp[b * (49*FDIM) + i];
  if (tid < 18) bnl[tid] = bnp[tid];
  if (tid >= 64 && tid < 112) db[tid - 64] = dists[b * 49 + (tid - 64)];
  __syncthreads();

  // ---- rope trig from RAW features 8,9 ; BN features {0..7,10} in place
  if (tid < 49) {
    float x = raw[tid][8], y = raw[tid][9];
    cs8[tid][0] = cosf(10.f * x); cs8[tid][1] = cosf(10.f * y);
    cs8[tid][2] = cosf(x);        cs8[tid][3] = cosf(y);
    cs8[tid][4] = sinf(10.f * x); cs8[tid][5] = sinf(10.f * y);
    cs8[tid][6] = sinf(x);        cs8[tid][7] = sinf(y);
  }
  for (int i = tid; i < 441; i += 256) {   // 49*9
    int t = i / 9, j = i - t * 9;
    int f = (j < 8) ? j : 10;
    raw[t][f] = raw[t][f] * bnl[j] + bnl[9 + j];
  }
  __syncthreads();

  if (s == 0 && tid < 10) enc[b * 138 + 128 + tid] = raw[48][tid];

  // ---- embed layer 1 -> KB
  if (s == 0) {
    const float bias1 = xe_b1[lane];
    float acc[13];
#pragma unroll
    for (int j = 0; j < 13; ++j) acc[j] = bias1;
#pragma unroll
    for (int k = 0; k < 8; ++k) {
      float w = xe_w1[k * 64 + lane];
#pragma unroll
      for (int j = 0; j < 13; ++j) {
        int t = grp + 4 * j;
        if (t < 49) acc[j] += raw[t][k] * w;
      }
    }
#pragma unroll
    for (int j = 0; j < 13; ++j) {
      int t = grp + 4 * j;
      if (t < 49) { float a = acc[j]; KB[t][lane] = a - tanhf(a); }
    }
  } else {
    const float w1y = ye_w1[lane];
    const float b1y = ye_b1[lane];
#pragma unroll
    for (int j = 0; j < 12; ++j) {
      int t = grp + 4 * j;
      float a = raw[t][10] * w1y + b1y;
      KB[t][lane] = a - tanhf(a);
    }
  }
  __syncthreads();

  // ---- embed layer 2 -> emb ; init Hs
  if (s == 0) {
    const float b2 = xe_b2[lane];
    float acc[13];
#pragma unroll
    for (int j = 0; j < 13; ++j) acc[j] = b2;
    for (int k = 0; k < 64; k += 4) {
      float w0 = xe_w2[(k + 0) * 64 + lane];
      float w1_ = xe_w2[(k + 1) * 64 + lane];
      float w2_ = xe_w2[(k + 2) * 64 + lane];
      float w3_ = xe_w2[(k + 3) * 64 + lane];
#pragma unroll
      for (int j = 0; j < 13; ++j) {
        int t = grp + 4 * j;
        if (t < 49) {
          float4 cv = *(const float4*)&KB[t][k];
          acc[j] += cv.x * w0 + cv.y * w1_ + cv.z * w2_ + cv.w * w3_;
        }
      }
    }
#pragma unroll
    for (int j = 0; j < 13; ++j) {
      int t = grp + 4 * j;
      if (t < 49) emb[t][lane] = acc[j];
    }
  } else {
    const float b2 = ye_b2[lane];
    float acc[12];
#pragma unroll
    for (int j = 0; j < 12; ++j) acc[j] = b2;
    for (int k = 0; k < 64; k += 4) {
      float w0 = ye_w2[(k + 0) * 64 + lane];
      float w1_ = ye_w2[(k + 1) * 64 + lane];
      float w2_ = ye_w2[(k + 2) * 64 + lane];
      float w3_ = ye_w2[(k + 3) * 64 + lane];
#pragma unroll
      for (int j = 0; j < 12; ++j) {
        float4 cv = *(const float4*)&KB[grp + 4 * j][k];
        acc[j] += cv.x * w0 + cv.y * w1_ + cv.z * w2_ + cv.w * w3_;
      }
    }
#pragma unroll
    for (int j = 0; j < 12; ++j) emb[grp + 4 * j][lane] = acc[j];
    if (tid < 64) emb[48][lane] = learnable_y[lane];
  }
  Hs[grp][lane] = hidden_tokens[grp * 64 + lane];
  __syncthreads();

  // ---- 2 self-attention layers
#pragma unroll 1
  for (int l = 0; l < 2; ++l) {
    const float* Wk_p = Wk + ((l * 2 + s) << 12);
    const float* Wv_p = Wv + ((l * 2 + s) << 12);
    const float* Wo_p = Wo + ((l * 2 + s) << 12);
    // q: layer 0 is batch-independent (precomputed); layer 1 = H @ Wq
    if (l == 0) {
      qb[grp][lane] = q0g[s * 256 + tid];
    } else {
      const float* Wq_p = Wq + ((l * 2 + s) << 12);
      float a = 0.f;
      for (int k = 0; k < 64; k += 4) {
        float4 hv = *(const float4*)&Hs[grp][k];
        a += hv.x * Wq_p[(k + 0) * 64 + lane] + hv.y * Wq_p[(k + 1) * 64 + lane]
           + hv.z * Wq_p[(k + 2) * 64 + lane] + hv.w * Wq_p[(k + 3) * 64 + lane];
      }
      qb[grp][lane] = a;
    }
    // K = rope(ctx @ Wk)  (12 rows per thread)
    {
      float aK[12];
#pragma unroll
      for (int j = 0; j < 12; ++j) aK[j] = 0.f;
      for (int k = 0; k < 64; k += 4) {
        float wk0 = Wk_p[(k + 0) * 64 + lane], wk1 = Wk_p[(k + 1) * 64 + lane];
        float wk2 = Wk_p[(k + 2) * 64 + lane], wk3 = Wk_p[(k + 3) * 64 + lane];
#pragma unroll
        for (int j = 0; j < 12; ++j) {
          float4 cv = *(const float4*)&emb[grp + 4 * j][k];
          aK[j] += cv.x * wk0 + cv.y * wk1 + cv.z * wk2 + cv.w * wk3;
        }
      }
      const int p = (lane >> 1) & 3;
      const int odd = lane & 1;
#pragma unroll
      for (int j = 0; j < 12; ++j) {
        int t = grp + 4 * j;
        float other = __shfl_xor(aK[j], 1);
        float co = cs8[t][p], si = cs8[t][4 + p];
        KB[t][lane] = odd ? (si * other + co * aK[j]) : (co * aK[j] - si * other);
      }
    }
    __syncthreads();
    // scores + bias
    {
      int r = tid >> 3;
      int h = r >> 2, i = r & 3;
      int t0 = tid & 7;
      for (int t = t0; t < 48; t += 8) {
        float a = 0.f;
#pragma unroll
        for (int d = 0; d < 8; ++d) a += qb[i][h * 8 + d] * KB[t][h * 8 + d];
        scb[r][t] = a * scale - db[t];
      }
    }
    __syncthreads();
    // softmax: 8 lanes per row
    {
      int r = tid >> 3, l8 = tid & 7;
      float v[6];
      float m = -1e30f;
#pragma unroll
      for (int j = 0; j < 6; ++j) { v[j] = scb[r][l8 + 8 * j]; m = fmaxf(m, v[j]); }
      m = fmaxf(m, __shfl_xor(m, 1));
      m = fmaxf(m, __shfl_xor(m, 2));
      m = fmaxf(m, __shfl_xor(m, 4));
      float sum = 0.f;
#pragma unroll
      for (int j = 0; j < 6; ++j) { v[j] = __expf(v[j] - m); sum += v[j]; }
      sum += __shfl_xor(sum, 1);
      sum += __shfl_xor(sum, 2);
      sum += __shfl_xor(sum, 4);
      float inv = 1.f / sum;
#pragma unroll
      for (int j = 0; j < 6; ++j) scb[r][l8 + 8 * j] = v[j] * inv;
    }
    __syncthreads();
    // T = a @ ctx  (32 x 64), rows r = grp + 4m  -> KB
    {
      float acc[8];
#pragma unroll
      for (int m = 0; m < 8; ++m) acc[m] = 0.f;
      for (int tt = 0; tt < 48; tt += 4) {
        float e0 = emb[tt + 0][lane], e1 = emb[tt + 1][lane];
        float e2 = emb[tt + 2][lane], e3 = emb[tt + 3][lane];
#pragma unroll
        for (int m = 0; m < 8; ++m) {
          float4 sc4 = *(const float4*)&scb[grp + 4 * m][tt];
          acc[m] += sc4.x * e0 + sc4.y * e1 + sc4.z * e2 + sc4.w * e3;
        }
      }
#pragma unroll
      for (int m = 0; m < 8; ++m) KB[grp + 4 * m][lane] = acc[m];
    }
    __syncthreads();
    // out[i][lane] = sum_c T[h*4+i][c] * Wv[c][lane]   (h = lane>>3) -> qb
    {
      const int r = ((lane >> 3) << 2) + grp;
      float a = 0.f;
      for (int c = 0; c < 64; c += 4) {
        float4 tv = *(const float4*)&KB[r][c];
        a += tv.x * Wv_p[(c + 0) * 64 + lane] + tv.y * Wv_p[(c + 1) * 64 + lane]
           + tv.z * Wv_p[(c + 2) * 64 + lane] + tv.w * Wv_p[(c + 3) * 64 + lane];
      }
      qb[grp][lane] = a;
    }
    __syncthreads();
    // H += out @ Wo
    {
      float a = Hs[grp][lane];
      for (int k = 0; k < 64; k += 4) {
        float4 av = *(const float4*)&qb[grp][k];
        a += av.x * Wo_p[(k + 0) * 64 + lane] + av.y * Wo_p[(k + 1) * 64 + lane]
           + av.z * Wo_p[(k + 2) * 64 + lane] + av.w * Wo_p[(k + 3) * 64 + lane];
      }
      Hs[grp][lane] = a;
    }
    __syncthreads();
  }

  // ---- final cross attention
  const float* Wq2_p = Wq2 + (s << 12);
  const float* Wk2_p = Wk2 + (s << 12);
  const float* Wv2_p = Wv2 + (s << 12);
  const float* Wo2_p = Wo2 + (s << 12);
  if (tid < 64) {
    float a = 0.f;
    for (int k = 0; k < 64; k += 4) {
      float4 cv = *(const float4*)&emb[48][k];
      a += cv.x * Wq2_p[(k + 0) * 64 + lane] + cv.y * Wq2_p[(k + 1) * 64 + lane]
         + cv.z * Wq2_p[(k + 2) * 64 + lane] + cv.w * Wq2_p[(k + 3) * 64 + lane];
    }
    float other = __shfl_xor(a, 1);
    int p = (lane >> 1) & 3;
    float co = cs8[48][p], si = cs8[48][4 + p];
    q2[lane] = (lane & 1) ? (si * other + co * a) : (co * a - si * other);
  }
  {
    float aK = 0.f, aV = 0.f;
    for (int k = 0; k < 64; k += 4) {
      float4 hv = *(const float4*)&Hs[grp][k];
      aK += hv.x * Wk2_p[(k + 0) * 64 + lane] + hv.y * Wk2_p[(k + 1) * 64 + lane]
          + hv.z * Wk2_p[(k + 2) * 64 + lane] + hv.w * Wk2_p[(k + 3) * 64 + lane];
      aV += hv.x * Wv2_p[(k + 0) * 64 + lane] + hv.y * Wv2_p[(k + 1) * 64 + lane]
          + hv.z * Wv2_p[(k + 2) * 64 + lane] + hv.w * Wv2_p[(k + 3) * 64 + lane];
    }
    KB[grp][lane] = aK;      // k2 rows 0..3
    KB[8 + grp][lane] = aV;  // v2 rows 8..11
  }
  __syncthreads();
  if (tid < 32) {
    int h = tid >> 2, i = tid & 3;
    float a = 0.f;
#pragma unroll
    for (int d = 0; d < 8; ++d) a += q2[h * 8 + d] * KB[i][h * 8 + d];
    a *= scale;
    float m = fmaxf(a, __shfl_xor(a, 1));
    m = fmaxf(m, __shfl_xor(m, 2));
    float e = __expf(a - m);
    float sum = e + __shfl_xor(e, 1);
    sum += __shfl_xor(sum, 2);
    a2[tid] = e / sum;
  }
  __syncthreads();
  if (tid < 64) {
    int h = lane >> 3;
    float a = 0.f;
#pragma unroll
    for (int i = 0; i < 4; ++i) a += a2[h * 4 + i] * KB[8 + i][lane];
    o1[lane] = a;
  }
  __syncthreads();
  if (tid < 64) {
    float a = 0.f;
    for (int k = 0; k < 64; k += 4) {
      float4 ov = *(const float4*)&o1[k];
      a += ov.x * Wo2_p[(k + 0) * 64 + lane] + ov.y * Wo2_p[(k + 1) * 64 + lane]
         + ov.z * Wo2_p[(k + 2) * 64 + lane] + ov.w * Wo2_p[(k + 3) * 64 + lane];
    }
    enc[b * 138 + s * 64 + lane] = a;
  }
}

// ---------------- decoder: enc(138) -> 512 -> 256 -> 1, 16 batches/block ----
__global__ __launch_bounds__(256) void k_dec(
    const float* __restrict__ enc,
    const float* __restrict__ w0, const float* __restrict__ b0,
    const float* __restrict__ w1, const float* __restrict__ b1,
    const float* __restrict__ w2, const float* __restrict__ b2,
    float* __restrict__ out)
{
  __shared__ float encs[16][140];
  __shared__ float h0s[16][512];
  __shared__ float h1s[16][256];
  const int tid = threadIdx.x;
  const int rb = blockIdx.x * 16;

  for (int i = tid; i < 16 * 138; i += 256) {
    int r = i / 138, k = i - r * 138;
    encs[r][k] = enc[(rb + r) * 138 + k];
  }
  __syncthreads();
  {
    float acc0[16], acc1[16];
    const float bb0 = b0[tid], bb1 = b0[tid + 256];
#pragma unroll
    for (int r = 0; r < 16; ++r) { acc0[r] = bb0; acc1[r] = bb1; }
    for (int k = 0; k < 136; k += 4) {
      float wa0 = w0[(k + 0) * 512 + tid], wa1 = w0[(k + 1) * 512 + tid];
      float wa2 = w0[(k + 2) * 512 + tid], wa3 = w0[(k + 3) * 512 + tid];
      float wb0 = w0[(k + 0) * 512 + tid + 256], wb1 = w0[(k + 1) * 512 + tid + 256];
      float wb2 = w0[(k + 2) * 512 + tid + 256], wb3 = w0[(k + 3) * 512 + tid + 256];
#pragma unroll
      for (int r = 0; r < 16; ++r) {
        float4 ev = *(const float4*)&encs[r][k];
        acc0[r] += ev.x * wa0 + ev.y * wa1 + ev.z * wa2 + ev.w * wa3;
        acc1[r] += ev.x * wb0 + ev.y * wb1 + ev.z * wb2 + ev.w * wb3;
      }
    }
    for (int k = 136; k < 138; ++k) {
      float wa = w0[k * 512 + tid], wb = w0[k * 512 + tid + 256];
#pragma unroll
      for (int r = 0; r < 16; ++r) {
        float e = encs[r][k];
        acc0[r] += e * wa; acc1[r] += e * wb;
      }
    }
#pragma unroll
    for (int r = 0; r < 16; ++r) {
      float a = acc0[r]; h0s[r][tid] = a - tanhf(a);
      a = acc1[r];       h0s[r][tid + 256] = a - tanhf(a);
    }
  }
  __syncthreads();
  {
    float acc[16];
    const float bb = b1[tid];
#pragma unroll
    for (int r = 0; r < 16; ++r) acc[r] = bb;
    for (int k = 0; k < 512; k += 4) {
      float ww0 = w1[(k + 0) * 256 + tid], ww1 = w1[(k + 1) * 256 + tid];
      float ww2 = w1[(k + 2) * 256 + tid], ww3 = w1[(k + 3) * 256 + tid];
#pragma unroll
      for (int r = 0; r < 16; ++r) {
        float4 hv = *(const float4*)&h0s[r][k];
        acc[r] += hv.x * ww0 + hv.y * ww1 + hv.z * ww2 + hv.w * ww3;
      }
    }
#pragma unroll
    for (int r = 0; r < 16; ++r) { float a = acc[r]; h1s[r][tid] = a - tanhf(a); }
  }
  __syncthreads();
  {
    int r = tid >> 4, l16 = tid & 15;
    float a = 0.f;
    for (int kk = 0; kk < 16; ++kk) {
      int k = l16 + 16 * kk;
      a += h1s[r][k] * w2[k];
    }
    for (int off = 8; off; off >>= 1) a += __shfl_down(a, off, 16);
    if (l16 == 0) out[rb + r] = a + b2[0];
  }
}

extern "C" void kernel_launch(void* const* d_in, const int* in_sizes, int n_in,
                              void* d_out, int out_size, void* d_ws, size_t ws_size,
                              hipStream_t stream) {
  const float* inp        = (const float*)d_in[0];
  const float* dists      = (const float*)d_in[1];
  const float* bn_gamma   = (const float*)d_in[3];
  const float* bn_beta    = (const float*)d_in[4];
  const float* xe_w1      = (const float*)d_in[5];
  const float* xe_b1      = (const float*)d_in[6];
  const float* xe_w2      = (const float*)d_in[7];
  const float* xe_b2      = (const float*)d_in[8];
  const float* ye_w1      = (const float*)d_in[9];
  const float* ye_b1      = (const float*)d_in[10];
  const float* ye_w2      = (const float*)d_in[11];
  const float* ye_b2      = (const float*)d_in[12];
  const float* learnable  = (const float*)d_in[13];
  const float* hidden     = (const float*)d_in[14];
  const float* Wq         = (const float*)d_in[15];
  const float* Wk         = (const float*)d_in[16];
  const float* Wv         = (const float*)d_in[17];
  const float* Wo         = (const float*)d_in[18];
  const float* Wq2        = (const float*)d_in[19];
  const float* Wk2        = (const float*)d_in[20];
  const float* Wv2        = (const float*)d_in[21];
  const float* Wo2        = (const float*)d_in[22];
  const float* dec_w0     = (const float*)d_in[23];
  const float* dec_b0     = (const float*)d_in[24];
  const float* dec_w1     = (const float*)d_in[25];
  const float* dec_b1     = (const float*)d_in[26];
  const float* dec_w2     = (const float*)d_in[27];
  const float* dec_b2     = (const float*)d_in[28];

  double* gsum = (double*)d_ws;                       // 18 doubles @ 0
  float*  bnp  = (float*)((char*)d_ws + 256);         // 18 floats
  float*  q0g  = (float*)((char*)d_ws + 512);         // 2*4*64 floats
  float*  enc  = (float*)((char*)d_ws + 2560);        // 8192*138 floats

  hipMemsetAsync(d_ws, 0, 256, stream);
  k_stats   <<<512, 256, 0, stream>>>(inp, gsum);
  k_finalize<<<1, 256, 0, stream>>>(gsum, bn_gamma, bn_beta, hidden, Wq, bnp, q0g);
  k_mega    <<<BS * 2, 256, 0, stream>>>(inp, dists, bnp, q0g,
                                         xe_w1, xe_b1, xe_w2, xe_b2,
                                         ye_w1, ye_b1, ye_w2, ye_b2,
                                         learnable, hidden,
                                         Wq, Wk, Wv, Wo, Wq2, Wk2, Wv2, Wo2, enc);
  k_dec     <<<BS / 16, 256, 0, stream>>>(enc, dec_w0, dec_b0, dec_w1, dec_b1,
                                          dec_w2, dec_b2, (float*)d_out);
}

// Round 5
// 1009.051 us; speedup vs baseline: 5.7733x; 1.0178x over previous
//
#include <hip/hip_runtime.h>
#include <math.h>

#define BS 8192
#define SL 49
#define FDIM 11
#define ROWS (BS*SL)

__device__ __forceinline__ float tanhshrink_f(float x) {
  // x - tanh(x), tanh = 1 - 2/(e^{2x}+1). Robust at +-inf of exp.
  float e = __expf(2.f * x);
  return (x - 1.f) + __fdividef(2.f, e + 1.f);
}

// ---------------- BN stats: sum / sumsq over (BS,SL) for features {0..7,10} ----
__global__ __launch_bounds__(256) void k_stats(const float* __restrict__ inp,
                                               double* __restrict__ gsum) {
  const int nblk = gridDim.x;
  const int per = (ROWS + nblk - 1) / nblk;
  const int r0 = blockIdx.x * per;
  int r1 = r0 + per; if (r1 > ROWS) r1 = ROWS;
  float s[9], q[9];
#pragma unroll
  for (int j = 0; j < 9; ++j) { s[j] = 0.f; q[j] = 0.f; }
  for (int r = r0 + threadIdx.x; r < r1; r += 256) {
    const float* row = inp + r * FDIM;
#pragma unroll
    for (int j = 0; j < 9; ++j) {
      float v = row[j < 8 ? j : 10];
      s[j] += v; q[j] += v * v;
    }
  }
#pragma unroll
  for (int j = 0; j < 9; ++j) {
    for (int off = 32; off; off >>= 1) {
      s[j] += __shfl_down(s[j], off);
      q[j] += __shfl_down(q[j], off);
    }
  }
  __shared__ float red[4][18];
  const int wid = threadIdx.x >> 6;
  const int lane = threadIdx.x & 63;
  if (lane == 0) {
#pragma unroll
    for (int j = 0; j < 9; ++j) { red[wid][j] = s[j]; red[wid][9 + j] = q[j]; }
  }
  __syncthreads();
  if (threadIdx.x < 18) {
    float t = red[0][threadIdx.x] + red[1][threadIdx.x] +
              red[2][threadIdx.x] + red[3][threadIdx.x];
    atomicAdd(&gsum[threadIdx.x], (double)t);
  }
}

// ---------------- finalize BN params + precompute layer-0 q (batch-independent) ----
__global__ __launch_bounds__(256) void k_finalize(const double* __restrict__ gsum,
                           const float* __restrict__ gamma,
                           const float* __restrict__ beta,
                           const float* __restrict__ hidden,
                           const float* __restrict__ Wq,
                           float* __restrict__ bnp,
                           float* __restrict__ q0g) {
  int tid = threadIdx.x;
  if (tid < 9) {
    const double N = (double)ROWS;
    double mean = gsum[tid] / N;
    double msq  = gsum[9 + tid] / N;
    float var = (float)(msq - mean * mean);
    float sc = gamma[tid] / sqrtf(var + 1e-5f);
    bnp[tid] = sc;
    bnp[9 + tid] = beta[tid] - (float)mean * sc;
  }
  // q0[s][i][c] = sum_k hidden[i][k] * Wq[l=0,s][k][c]
  int s = tid >> 7, i2 = (tid >> 6) & 1, c = tid & 63;
  const float* W = Wq + (s << 12);
#pragma unroll
  for (int ii = 0; ii < 2; ++ii) {
    int i = i2 + 2 * ii;
    float a = 0.f;
    for (int k = 0; k < 64; ++k) a += hidden[i * 64 + k] * W[k * 64 + c];
    q0g[s * 256 + i * 64 + c] = a;
  }
}

// ---------------- mega kernel: one block per (batch, stream) ----------------
// LDS budget ~39.5 KB -> 4 blocks/CU.
__global__ __launch_bounds__(256, 4) void k_mega(
    const float* __restrict__ inp, const float* __restrict__ dists,
    const float* __restrict__ bnp, const float* __restrict__ q0g,
    const float* __restrict__ xe_w1, const float* __restrict__ xe_b1,
    const float* __restrict__ xe_w2, const float* __restrict__ xe_b2,
    const float* __restrict__ ye_w1, const float* __restrict__ ye_b1,
    const float* __restrict__ ye_w2, const float* __restrict__ ye_b2,
    const float* __restrict__ learnable_y, const float* __restrict__ hidden_tokens,
    const float* __restrict__ Wq, const float* __restrict__ Wk,
    const float* __restrict__ Wv, const float* __restrict__ Wo,
    const float* __restrict__ Wq2, const float* __restrict__ Wk2,
    const float* __restrict__ Wv2, const float* __restrict__ Wo2,
    float* __restrict__ enc)
{
  __shared__ float raw[49][12];
  __shared__ float cs8[49][8];
  __shared__ float emb[49][64];   // this stream's embedding (ctx rows 0..47, qry row 48)
  __shared__ float KB[49][68];    // staged h1, then K (rope'd), then T = a@ctx, then k2/v2
  __shared__ float scb[32][52];   // softmax probs (row stride 52 -> 16B aligned)
  __shared__ float Hs[4][64];
  __shared__ float qb[4][64];     // q, then attn-out
  __shared__ float db[48];
  __shared__ float bnl[18];
  __shared__ float q2[64];
  __shared__ float o1[64];
  __shared__ float a2[32];

  const int tid  = threadIdx.x;
  const int lane = tid & 63;
  const int grp  = tid >> 6;
  const int b    = blockIdx.x >> 1;
  const int s    = blockIdx.x & 1;
  const float scale = 0.35355339059327373f;  // 1/sqrt(8)

  // ---- load input rows, bn params, dists
  for (int i = tid; i < 49 * FDIM; i += 256) raw[i / FDIM][i % FDIM] = inp[b * (49*FDIM) + i];
  if (tid < 18) bnl[tid] = bnp[tid];
  if (tid >= 64 && tid < 112) db[tid - 64] = dists[b * 49 + (tid - 64)];
  __syncthreads();

  // ---- rope trig from RAW features 8,9 ; BN features {0..7,10} in place
  if (tid < 49) {
    float x = raw[tid][8], y = raw[tid][9];
    cs8[tid][0] = cosf(10.f * x); cs8[tid][1] = cosf(10.f * y);
    cs8[tid][2] = cosf(x);        cs8[tid][3] = cosf(y);
    cs8[tid][4] = sinf(10.f * x); cs8[tid][5] = sinf(10.f * y);
    cs8[tid][6] = sinf(x);        cs8[tid][7] = sinf(y);
  }
  for (int i = tid; i < 441; i += 256) {   // 49*9
    int t = i / 9, j = i - t * 9;
    int f = (j < 8) ? j : 10;
    raw[t][f] = raw[t][f] * bnl[j] + bnl[9 + j];
  }
  __syncthreads();

  if (s == 0 && tid < 10) enc[b * 138 + 128 + tid] = raw[48][tid];

  // ---- embed layer 1 -> KB
  if (s == 0) {
    const float bias1 = xe_b1[lane];
    float acc[13];
#pragma unroll
    for (int j = 0; j < 13; ++j) acc[j] = bias1;
#pragma unroll
    for (int k = 0; k < 8; ++k) {
      float w = xe_w1[k * 64 + lane];
#pragma unroll
      for (int j = 0; j < 13; ++j) {
        int t = grp + 4 * j;
        if (t < 49) acc[j] += raw[t][k] * w;
      }
    }
#pragma unroll
    for (int j = 0; j < 13; ++j) {
      int t = grp + 4 * j;
      if (t < 49) KB[t][lane] = tanhshrink_f(acc[j]);
    }
  } else {
    const float w1y = ye_w1[lane];
    const float b1y = ye_b1[lane];
#pragma unroll
    for (int j = 0; j < 12; ++j) {
      int t = grp + 4 * j;
      KB[t][lane] = tanhshrink_f(raw[t][10] * w1y + b1y);
    }
  }
  __syncthreads();

  // ---- embed layer 2 -> emb ; init Hs
  if (s == 0) {
    const float b2 = xe_b2[lane];
    float acc[13];
#pragma unroll
    for (int j = 0; j < 13; ++j) acc[j] = b2;
    for (int k = 0; k < 64; k += 4) {
      float w0 = xe_w2[(k + 0) * 64 + lane];
      float w1_ = xe_w2[(k + 1) * 64 + lane];
      float w2_ = xe_w2[(k + 2) * 64 + lane];
      float w3_ = xe_w2[(k + 3) * 64 + lane];
#pragma unroll
      for (int j = 0; j < 13; ++j) {
        int t = grp + 4 * j;
        if (t < 49) {
          float4 cv = *(const float4*)&KB[t][k];
          acc[j] += cv.x * w0 + cv.y * w1_ + cv.z * w2_ + cv.w * w3_;
        }
      }
    }
#pragma unroll
    for (int j = 0; j < 13; ++j) {
      int t = grp + 4 * j;
      if (t < 49) emb[t][lane] = acc[j];
    }
  } else {
    const float b2 = ye_b2[lane];
    float acc[12];
#pragma unroll
    for (int j = 0; j < 12; ++j) acc[j] = b2;
    for (int k = 0; k < 64; k += 4) {
      float w0 = ye_w2[(k + 0) * 64 + lane];
      float w1_ = ye_w2[(k + 1) * 64 + lane];
      float w2_ = ye_w2[(k + 2) * 64 + lane];
      float w3_ = ye_w2[(k + 3) * 64 + lane];
#pragma unroll
      for (int j = 0; j < 12; ++j) {
        float4 cv = *(const float4*)&KB[grp + 4 * j][k];
        acc[j] += cv.x * w0 + cv.y * w1_ + cv.z * w2_ + cv.w * w3_;
      }
    }
#pragma unroll
    for (int j = 0; j < 12; ++j) emb[grp + 4 * j][lane] = acc[j];
    if (tid < 64) emb[48][lane] = learnable_y[lane];
  }
  Hs[grp][lane] = hidden_tokens[grp * 64 + lane];
  __syncthreads();

  // ---- 2 self-attention layers
#pragma unroll 1
  for (int l = 0; l < 2; ++l) {
    const float* Wk_p = Wk + ((l * 2 + s) << 12);
    const float* Wv_p = Wv + ((l * 2 + s) << 12);
    const float* Wo_p = Wo + ((l * 2 + s) << 12);
    // q: layer 0 is batch-independent (precomputed); layer 1 = H @ Wq
    if (l == 0) {
      qb[grp][lane] = q0g[s * 256 + tid];
    } else {
      const float* Wq_p = Wq + ((l * 2 + s) << 12);
      float a = 0.f;
      for (int k = 0; k < 64; k += 4) {
        float4 hv = *(const float4*)&Hs[grp][k];
        a += hv.x * Wq_p[(k + 0) * 64 + lane] + hv.y * Wq_p[(k + 1) * 64 + lane]
           + hv.z * Wq_p[(k + 2) * 64 + lane] + hv.w * Wq_p[(k + 3) * 64 + lane];
      }
      qb[grp][lane] = a;
    }
    // K = rope(ctx @ Wk)  (12 rows per thread)
    {
      float aK[12];
#pragma unroll
      for (int j = 0; j < 12; ++j) aK[j] = 0.f;
      for (int k = 0; k < 64; k += 4) {
        float wk0 = Wk_p[(k + 0) * 64 + lane], wk1 = Wk_p[(k + 1) * 64 + lane];
        float wk2 = Wk_p[(k + 2) * 64 + lane], wk3 = Wk_p[(k + 3) * 64 + lane];
#pragma unroll
        for (int j = 0; j < 12; ++j) {
          float4 cv = *(const float4*)&emb[grp + 4 * j][k];
          aK[j] += cv.x * wk0 + cv.y * wk1 + cv.z * wk2 + cv.w * wk3;
        }
      }
      const int p = (lane >> 1) & 3;
      const int odd = lane & 1;
#pragma unroll
      for (int j = 0; j < 12; ++j) {
        int t = grp + 4 * j;
        float other = __shfl_xor(aK[j], 1);
        float co = cs8[t][p], si = cs8[t][4 + p];
        KB[t][lane] = odd ? (si * other + co * aK[j]) : (co * aK[j] - si * other);
      }
    }
    __syncthreads();
    // scores + softmax fused: scores stay in registers, only probs hit LDS
    {
      const int t0 = tid & 7;
      const int i  = (tid >> 3) & 3;
      const int h  = tid >> 5;
      const int r  = tid >> 3;
      float4 qa = *(const float4*)&qb[i][h * 8];
      float4 qc = *(const float4*)&qb[i][h * 8 + 4];
      float v[6];
#pragma unroll
      for (int j = 0; j < 6; ++j) {
        int t = t0 + 8 * j;
        float4 ka = *(const float4*)&KB[t][h * 8];
        float4 kc = *(const float4*)&KB[t][h * 8 + 4];
        float a = qa.x * ka.x + qa.y * ka.y + qa.z * ka.z + qa.w * ka.w
                + qc.x * kc.x + qc.y * kc.y + qc.z * kc.z + qc.w * kc.w;
        v[j] = a * scale - db[t];
      }
      float m = fmaxf(fmaxf(fmaxf(v[0], v[1]), fmaxf(v[2], v[3])), fmaxf(v[4], v[5]));
      m = fmaxf(m, __shfl_xor(m, 1));
      m = fmaxf(m, __shfl_xor(m, 2));
      m = fmaxf(m, __shfl_xor(m, 4));
      float sum = 0.f;
#pragma unroll
      for (int j = 0; j < 6; ++j) { v[j] = __expf(v[j] - m); sum += v[j]; }
      sum += __shfl_xor(sum, 1);
      sum += __shfl_xor(sum, 2);
      sum += __shfl_xor(sum, 4);
      float inv = 1.f / sum;
#pragma unroll
      for (int j = 0; j < 6; ++j) scb[r][t0 + 8 * j] = v[j] * inv;
    }
    __syncthreads();
    // T = a @ ctx  (32 x 64), rows r = grp + 4m  -> KB
    {
      float acc[8];
#pragma unroll
      for (int m = 0; m < 8; ++m) acc[m] = 0.f;
      for (int tt = 0; tt < 48; tt += 4) {
        float e0 = emb[tt + 0][lane], e1 = emb[tt + 1][lane];
        float e2 = emb[tt + 2][lane], e3 = emb[tt + 3][lane];
#pragma unroll
        for (int m = 0; m < 8; ++m) {
          float4 sc4 = *(const float4*)&scb[grp + 4 * m][tt];
          acc[m] += sc4.x * e0 + sc4.y * e1 + sc4.z * e2 + sc4.w * e3;
        }
      }
#pragma unroll
      for (int m = 0; m < 8; ++m) KB[grp + 4 * m][lane] = acc[m];
    }
    __syncthreads();
    // out[i][lane] = sum_c T[h*4+i][c] * Wv[c][lane]   (h = lane>>3) -> qb
    {
      const int r = ((lane >> 3) << 2) + grp;
      float a = 0.f;
      for (int c = 0; c < 64; c += 4) {
        float4 tv = *(const float4*)&KB[r][c];
        a += tv.x * Wv_p[(c + 0) * 64 + lane] + tv.y * Wv_p[(c + 1) * 64 + lane]
           + tv.z * Wv_p[(c + 2) * 64 + lane] + tv.w * Wv_p[(c + 3) * 64 + lane];
      }
      qb[grp][lane] = a;
    }
    __syncthreads();
    // H += out @ Wo
    {
      float a = Hs[grp][lane];
      for (int k = 0; k < 64; k += 4) {
        float4 av = *(const float4*)&qb[grp][k];
        a += av.x * Wo_p[(k + 0) * 64 + lane] + av.y * Wo_p[(k + 1) * 64 + lane]
           + av.z * Wo_p[(k + 2) * 64 + lane] + av.w * Wo_p[(k + 3) * 64 + lane];
      }
      Hs[grp][lane] = a;
    }
    __syncthreads();
  }

  // ---- final cross attention
  const float* Wq2_p = Wq2 + (s << 12);
  const float* Wk2_p = Wk2 + (s << 12);
  const float* Wv2_p = Wv2 + (s << 12);
  const float* Wo2_p = Wo2 + (s << 12);
  if (tid < 64) {
    float a = 0.f;
    for (int k = 0; k < 64; k += 4) {
      float4 cv = *(const float4*)&emb[48][k];
      a += cv.x * Wq2_p[(k + 0) * 64 + lane] + cv.y * Wq2_p[(k + 1) * 64 + lane]
         + cv.z * Wq2_p[(k + 2) * 64 + lane] + cv.w * Wq2_p[(k + 3) * 64 + lane];
    }
    float other = __shfl_xor(a, 1);
    int p = (lane >> 1) & 3;
    float co = cs8[48][p], si = cs8[48][4 + p];
    q2[lane] = (lane & 1) ? (si * other + co * a) : (co * a - si * other);
  }
  {
    float aK = 0.f, aV = 0.f;
    for (int k = 0; k < 64; k += 4) {
      float4 hv = *(const float4*)&Hs[grp][k];
      aK += hv.x * Wk2_p[(k + 0) * 64 + lane] + hv.y * Wk2_p[(k + 1) * 64 + lane]
          + hv.z * Wk2_p[(k + 2) * 64 + lane] + hv.w * Wk2_p[(k + 3) * 64 + lane];
      aV += hv.x * Wv2_p[(k + 0) * 64 + lane] + hv.y * Wv2_p[(k + 1) * 64 + lane]
          + hv.z * Wv2_p[(k + 2) * 64 + lane] + hv.w * Wv2_p[(k + 3) * 64 + lane];
    }
    KB[grp][lane] = aK;      // k2 rows 0..3
    KB[8 + grp][lane] = aV;  // v2 rows 8..11
  }
  __syncthreads();
  if (tid < 32) {
    int h = tid >> 2, i = tid & 3;
    float a = 0.f;
#pragma unroll
    for (int d = 0; d < 8; ++d) a += q2[h * 8 + d] * KB[i][h * 8 + d];
    a *= scale;
    float m = fmaxf(a, __shfl_xor(a, 1));
    m = fmaxf(m, __shfl_xor(m, 2));
    float e = __expf(a - m);
    float sum = e + __shfl_xor(e, 1);
    sum += __shfl_xor(sum, 2);
    a2[tid] = e / sum;
  }
  __syncthreads();
  if (tid < 64) {
    int h = lane >> 3;
    float a = 0.f;
#pragma unroll
    for (int i = 0; i < 4; ++i) a += a2[h * 4 + i] * KB[8 + i][lane];
    o1[lane] = a;
  }
  __syncthreads();
  if (tid < 64) {
    float a = 0.f;
    for (int k = 0; k < 64; k += 4) {
      float4 ov = *(const float4*)&o1[k];
      a += ov.x * Wo2_p[(k + 0) * 64 + lane] + ov.y * Wo2_p[(k + 1) * 64 + lane]
         + ov.z * Wo2_p[(k + 2) * 64 + lane] + ov.w * Wo2_p[(k + 3) * 64 + lane];
    }
    enc[b * 138 + s * 64 + lane] = a;
  }
}

// ---------------- decoder: enc(138) -> 512 -> 256 -> 1, 16 batches/block ----
__global__ __launch_bounds__(256) void k_dec(
    const float* __restrict__ enc,
    const float* __restrict__ w0, const float* __restrict__ b0,
    const float* __restrict__ w1, const float* __restrict__ b1,
    const float* __restrict__ w2, const float* __restrict__ b2,
    float* __restrict__ out)
{
  __shared__ float encs[16][140];
  __shared__ float h0s[16][512];
  __shared__ float h1s[16][256];
  const int tid = threadIdx.x;
  const int rb = blockIdx.x * 16;

  for (int i = tid; i < 16 * 138; i += 256) {
    int r = i / 138, k = i - r * 138;
    encs[r][k] = enc[(rb + r) * 138 + k];
  }
  __syncthreads();
  {
    float acc0[16], acc1[16];
    const float bb0 = b0[tid], bb1 = b0[tid + 256];
#pragma unroll
    for (int r = 0; r < 16; ++r) { acc0[r] = bb0; acc1[r] = bb1; }
    for (int k = 0; k < 136; k += 4) {
      float wa0 = w0[(k + 0) * 512 + tid], wa1 = w0[(k + 1) * 512 + tid];
      float wa2 = w0[(k + 2) * 512 + tid], wa3 = w0[(k + 3) * 512 + tid];
      float wb0 = w0[(k + 0) * 512 + tid + 256], wb1 = w0[(k + 1) * 512 + tid + 256];
      float wb2 = w0[(k + 2) * 512 + tid + 256], wb3 = w0[(k + 3) * 512 + tid + 256];
#pragma unroll
      for (int r = 0; r < 16; ++r) {
        float4 ev = *(const float4*)&encs[r][k];
        acc0[r] += ev.x * wa0 + ev.y * wa1 + ev.z * wa2 + ev.w * wa3;
        acc1[r] += ev.x * wb0 + ev.y * wb1 + ev.z * wb2 + ev.w * wb3;
      }
    }
    for (int k = 136; k < 138; ++k) {
      float wa = w0[k * 512 + tid], wb = w0[k * 512 + tid + 256];
#pragma unroll
      for (int r = 0; r < 16; ++r) {
        float e = encs[r][k];
        acc0[r] += e * wa; acc1[r] += e * wb;
      }
    }
#pragma unroll
    for (int r = 0; r < 16; ++r) {
      float a = acc0[r]; h0s[r][tid] = a - tanhf(a);
      a = acc1[r];       h0s[r][tid + 256] = a - tanhf(a);
    }
  }
  __syncthreads();
  {
    float acc[16];
    const float bb = b1[tid];
#pragma unroll
    for (int r = 0; r < 16; ++r) acc[r] = bb;
    for (int k = 0; k < 512; k += 4) {
      float ww0 = w1[(k + 0) * 256 + tid], ww1 = w1[(k + 1) * 256 + tid];
      float ww2 = w1[(k + 2) * 256 + tid], ww3 = w1[(k + 3) * 256 + tid];
#pragma unroll
      for (int r = 0; r < 16; ++r) {
        float4 hv = *(const float4*)&h0s[r][k];
        acc[r] += hv.x * ww0 + hv.y * ww1 + hv.z * ww2 + hv.w * ww3;
      }
    }
#pragma unroll
    for (int r = 0; r < 16; ++r) { float a = acc[r]; h1s[r][tid] = a - tanhf(a); }
  }
  __syncthreads();
  {
    int r = tid >> 4, l16 = tid & 15;
    float a = 0.f;
    for (int kk = 0; kk < 16; ++kk) {
      int k = l16 + 16 * kk;
      a += h1s[r][k] * w2[k];
    }
    for (int off = 8; off; off >>= 1) a += __shfl_down(a, off, 16);
    if (l16 == 0) out[rb + r] = a + b2[0];
  }
}

extern "C" void kernel_launch(void* const* d_in, const int* in_sizes, int n_in,
                              void* d_out, int out_size, void* d_ws, size_t ws_size,
                              hipStream_t stream) {
  const float* inp        = (const float*)d_in[0];
  const float* dists      = (const float*)d_in[1];
  const float* bn_gamma   = (const float*)d_in[3];
  const float* bn_beta    = (const float*)d_in[4];
  const float* xe_w1      = (const float*)d_in[5];
  const float* xe_b1      = (const float*)d_in[6];
  const float* xe_w2      = (const float*)d_in[7];
  const float* xe_b2      = (const float*)d_in[8];
  const float* ye_w1      = (const float*)d_in[9];
  const float* ye_b1      = (const float*)d_in[10];
  const float* ye_w2      = (const float*)d_in[11];
  const float* ye_b2      = (const float*)d_in[12];
  const float* learnable  = (const float*)d_in[13];
  const float* hidden     = (const float*)d_in[14];
  const float* Wq         = (const float*)d_in[15];
  const float* Wk         = (const float*)d_in[16];
  const float* Wv         = (const float*)d_in[17];
  const float* Wo         = (const float*)d_in[18];
  const float* Wq2        = (const float*)d_in[19];
  const float* Wk2        = (const float*)d_in[20];
  const float* Wv2        = (const float*)d_in[21];
  const float* Wo2        = (const float*)d_in[22];
  const float* dec_w0     = (const float*)d_in[23];
  const float* dec_b0     = (const float*)d_in[24];
  const float* dec_w1     = (const float*)d_in[25];
  const float* dec_b1     = (const float*)d_in[26];
  const float* dec_w2     = (const float*)d_in[27];
  const float* dec_b2     = (const float*)d_in[28];

  double* gsum = (double*)d_ws;                       // 18 doubles @ 0
  float*  bnp  = (float*)((char*)d_ws + 256);         // 18 floats
  float*  q0g  = (float*)((char*)d_ws + 512);         // 2*4*64 floats
  float*  enc  = (float*)((char*)d_ws + 2560);        // 8192*138 floats

  hipMemsetAsync(d_ws, 0, 256, stream);
  k_stats   <<<512, 256, 0, stream>>>(inp, gsum);
  k_finalize<<<1, 256, 0, stream>>>(gsum, bn_gamma, bn_beta, hidden, Wq, bnp, q0g);
  k_mega    <<<BS * 2, 256, 0, stream>>>(inp, dists, bnp, q0g,
                                         xe_w1, xe_b1, xe_w2, xe_b2,
                                         ye_w1, ye_b1, ye_w2, ye_b2,
                                         learnable, hidden,
                                         Wq, Wk, Wv, Wo, Wq2, Wk2, Wv2, Wo2, enc);
  k_dec     <<<BS / 16, 256, 0, stream>>>(enc, dec_w0, dec_b0, dec_w1, dec_b1,
                                          dec_w2, dec_b2, (float*)d_out);
}